// Round 14
// baseline (1368.047 us; speedup 1.0000x reference)
//
#include <hip/hip_runtime.h>

#define B_    128
#define NSTEP 24
#define INL   512
#define OUTL  256
#define HL    1024
#define CL    1024
#define IH    (INL + HL)   // 1536
#define G_BLOCKS 256
#define NBLK   272         // persistent grid (256 gate + 16 outproj) = 17 groups x 16

typedef short          s16x8 __attribute__((ext_vector_type(8)));
typedef float          f32x4 __attribute__((ext_vector_type(4)));
typedef unsigned short u16x4 __attribute__((ext_vector_type(4)));
typedef unsigned short u16x8 __attribute__((ext_vector_type(8)));

// ---------- full-path ws layout ----------
// h, c BLOCK-MAJOR: off(b,j) = (j>>2)*512 + b*4 + (j&3)
// XW fp16: ((t*256 + jblk)*128 + b)*16 + jj*4 + g
// bar: per-step int[288]: group g ctr at [g*16] (64B padded), root at [272]
#define FWS_C    64
#define FWS_HA   (FWS_C + 524288)
#define FWS_HB   (FWS_HA + 262144)
#define FWS_BAR  (FWS_HB + 262144)
#define FWS_XW   (FWS_BAR + 28672)
#define FWS_END  (FWS_XW + 25165824)
#define BAR_INTS (24 * 288)
// ---------- fallback (R5, proven) ----------
#define WS_C  64
#define WS_HA (64 + 262144)
#define WS_HB (64 + 524288)

__device__ __forceinline__ float bits2f(unsigned short u) {
    union { unsigned u; float f; } w; w.u = ((unsigned)u) << 16; return w.f;
}
__device__ __forceinline__ unsigned short f2bf(float f) {
    union { float f; unsigned u; } w; w.f = f;
    unsigned r = (w.u + 0x7fffu + ((w.u >> 16) & 1u)) >> 16;   // RNE
    return (unsigned short)r;
}
__device__ __forceinline__ float sigmoidf_(float v) { return 1.0f / (1.0f + expf(-v)); }
__device__ __forceinline__ float sane(float v, float lim) {   // NaN -> bounded
    return fminf(fmaxf(v, -lim), lim);
}

template<int FP32>
__device__ __forceinline__ s16x8 load8(const void* base, size_t off) {
    if constexpr (FP32) {
        const float* p = (const float*)base + off;
        f32x4 a = *(const f32x4*)p;
        f32x4 b = *(const f32x4*)(p + 4);
        s16x8 r;
        r[0] = (short)f2bf(a[0]); r[1] = (short)f2bf(a[1]);
        r[2] = (short)f2bf(a[2]); r[3] = (short)f2bf(a[3]);
        r[4] = (short)f2bf(b[0]); r[5] = (short)f2bf(b[1]);
        r[6] = (short)f2bf(b[2]); r[7] = (short)f2bf(b[3]);
        return r;
    } else {
        return *(const s16x8*)((const unsigned short*)base + off);
    }
}
template<int FP32>
__device__ __forceinline__ float ld1(const void* base, size_t off) {
    if constexpr (FP32) return ((const float*)base)[off];
    else                return bits2f(((const unsigned short*)base)[off]);
}
template<int FP32>
__device__ __forceinline__ u16x4 ldcvt4(const void* base, size_t off) {
    if constexpr (FP32) {
        f32x4 v = *(const f32x4*)((const float*)base + off);
        u16x4 r;
        r[0] = f2bf(v[0]); r[1] = f2bf(v[1]); r[2] = f2bf(v[2]); r[3] = f2bf(v[3]);
        return r;
    } else {
        return *(const u16x4*)((const unsigned short*)base + off);
    }
}
// A-fragment (8 k-elems) from block-major h; k0 multiple of 8
__device__ __forceinline__ s16x8 ldh8(const unsigned short* __restrict__ h,
                                      int row, int k0) {
    const unsigned short* p = h + (size_t)(k0 >> 2) * 512 + row * 4;
    u16x4 lo = *(const u16x4*)p;
    u16x4 hi = *(const u16x4*)(p + 512);
    s16x8 r;
    r[0] = (short)lo[0]; r[1] = (short)lo[1]; r[2] = (short)lo[2]; r[3] = (short)lo[3];
    r[4] = (short)hi[0]; r[5] = (short)hi[1]; r[6] = (short)hi[2]; r[7] = (short)hi[3];
    return r;
}

// Two-level grid barrier: 17 groups x 16 blocks. Members release-add group
// counter (64B-padded); leader relaxed-polls, acquires, release-adds root;
// everyone relaxed-polls root; ONE acquire fence at exit. Max RMW contention
// 17 (R13's single counter serialized 272 RMWs per step).
__device__ __forceinline__ void grid_barrier2(int* __restrict__ slot, int blk, int tid) {
    __syncthreads();
    if (tid == 0) {
        const int g = blk >> 4;
        __hip_atomic_fetch_add(slot + g * 16, 1, __ATOMIC_RELEASE, __HIP_MEMORY_SCOPE_AGENT);
        if ((blk & 15) == 0) {
            while (__hip_atomic_load(slot + g * 16, __ATOMIC_RELAXED, __HIP_MEMORY_SCOPE_AGENT) < 16)
                __builtin_amdgcn_s_sleep(2);
            __threadfence();   // acquire: members' writes happen-before root release
            __hip_atomic_fetch_add(slot + 272, 1, __ATOMIC_RELEASE, __HIP_MEMORY_SCOPE_AGENT);
        }
        while (__hip_atomic_load(slot + 272, __ATOMIC_RELAXED, __HIP_MEMORY_SCOPE_AGENT) < 17)
            __builtin_amdgcn_s_sleep(2);
    }
    __syncthreads();
    __threadfence();            // single acquire: drop stale h/c lines once
}

// ---------------------------------------------------------------------------
// Dtype detector (verified flag=1/fp32 on this harness in R4).
// ---------------------------------------------------------------------------
__global__ void detect_kernel(const unsigned* __restrict__ xw, int* __restrict__ flag) {
    __shared__ int wild, zero;
    const int tid = threadIdx.x;
    if (tid == 0) { wild = 0; zero = 0; }
    __syncthreads();
    int w = 0, z = 0;
    for (int s = 0; s < 4; ++s) {
        unsigned short lo = (unsigned short)(xw[tid * 4 + s] & 0xffffu);
        float v = bits2f(lo);
        if (v == 0.0f) z++;
        else if (v == v && (fabsf(v) > 1e4f || fabsf(v) < 1e-8f)) w++;
    }
    atomicAdd(&wild, w);
    atomicAdd(&zero, z);
    __syncthreads();
    if (tid == 0) *flag = (wild > 128 || zero > 512) ? 1 : 0;
}

// ===========================================================================
// FULL PATH
// ===========================================================================

__global__ void init_full_kernel(const void* c0, const void* h0, const int* __restrict__ flag,
                                 float* __restrict__ c,
                                 unsigned short* __restrict__ hA,
                                 unsigned short* __restrict__ hB,
                                 int* __restrict__ bar)
{
    const int f   = *flag;
    const int idx = blockIdx.x * blockDim.x + threadIdx.x;
    if (idx < BAR_INTS) bar[idx] = 0;
    if (idx < B_ * CL) {
        const int j = ((idx >> 9) << 2) + (idx & 3);
        c[idx]  = f ? ((const float*)c0)[j] : bits2f(((const unsigned short*)c0)[j]);
        const float hv = f ? ((const float*)h0)[j] : bits2f(((const unsigned short*)h0)[j]);
        const unsigned short hb = f2bf(hv);
        hA[idx] = hb;
        hB[idx] = hb;
    }
}

// ---------------------------------------------------------------------------
// XW tile GEMM (R12 version, proven: LDS-staged contiguous stores).
// ---------------------------------------------------------------------------
#define XA_PITCH 40
template<int FP32>
__device__ __forceinline__ void xw_tile_body(
    const void* __restrict__ x,
    const void* __restrict__ W,  const void* __restrict__ Wi,
    const void* __restrict__ Wf, const void* __restrict__ Wo,
    _Float16* __restrict__ XW, int t, int j0,
    unsigned short* __restrict__ smem)
{
    unsigned short* Alds = smem;
    unsigned short* Blds = smem + 128 * XA_PITCH;

    const int tid  = threadIdx.x;
    const int lane = tid & 63;
    const int wv   = tid >> 6;
    const int c16  = lane & 15;
    const int kg   = lane >> 4;
    const int mq   = wv >> 1, nq = wv & 1;

    int rowc[4], colc[4];
    const void* wbase[4];
    size_t wrow[4];
    #pragma unroll
    for (int p = 0; p < 4; ++p) {
        const int cid = tid + p * 256;
        rowc[p] = cid >> 3;
        colc[p] = (cid & 7) * 4;
        const int g = rowc[p] >> 5;
        wbase[p] = (g == 0) ? W : (g == 1) ? Wi : (g == 2) ? Wf : Wo;
        wrow[p]  = ((size_t)(t * CL + j0 + (rowc[p] & 31))) * IH;
    }

    f32x4 acc[4][4];
    #pragma unroll
    for (int a = 0; a < 4; ++a)
        #pragma unroll
        for (int b = 0; b < 4; ++b) acc[a][b] = (f32x4){0.f, 0.f, 0.f, 0.f};

    u16x4 ra[4], rb[4];
    #pragma unroll
    for (int p = 0; p < 4; ++p) {
        ra[p] = ldcvt4<FP32>(wbase[p], wrow[p] + colc[p]);
        rb[p] = ldcvt4<FP32>(x,  ((size_t)(rowc[p] * NSTEP + t)) * INL + colc[p]);
    }

    for (int s = 0; s < 16; ++s) {
        __syncthreads();
        #pragma unroll
        for (int p = 0; p < 4; ++p) {
            *(u16x4*)(Alds + rowc[p] * XA_PITCH + colc[p]) = ra[p];
            *(u16x4*)(Blds + rowc[p] * XA_PITCH + colc[p]) = rb[p];
        }
        if (s < 15) {
            const int k0 = (s + 1) * 32;
            #pragma unroll
            for (int p = 0; p < 4; ++p) {
                ra[p] = ldcvt4<FP32>(wbase[p], wrow[p] + k0 + colc[p]);
                rb[p] = ldcvt4<FP32>(x,  ((size_t)(rowc[p] * NSTEP + t)) * INL + k0 + colc[p]);
            }
        }
        __syncthreads();
        s16x8 av[4], bv[4];
        #pragma unroll
        for (int mf = 0; mf < 4; ++mf)
            av[mf] = *(const s16x8*)(Alds + (mq * 64 + mf * 16 + c16) * XA_PITCH + kg * 8);
        #pragma unroll
        for (int nf = 0; nf < 4; ++nf)
            bv[nf] = *(const s16x8*)(Blds + (nq * 64 + nf * 16 + c16) * XA_PITCH + kg * 8);
        #pragma unroll
        for (int mf = 0; mf < 4; ++mf)
            #pragma unroll
            for (int nf = 0; nf < 4; ++nf)
                acc[mf][nf] = __builtin_amdgcn_mfma_f32_16x16x32_bf16(av[mf], bv[nf], acc[mf][nf], 0, 0, 0);
    }

    __syncthreads();
    _Float16* lc = (_Float16*)smem;   // [8 jblkL][128 b][4 jj][4 g] = 32 KB
    #pragma unroll
    for (int mf = 0; mf < 4; ++mf)
        #pragma unroll
        for (int nf = 0; nf < 4; ++nf)
            #pragma unroll
            for (int i = 0; i < 4; ++i) {
                const int jr = mq * 64 + mf * 16 + kg * 4 + i;
                const int bc = nq * 64 + nf * 16 + c16;
                const int g  = jr >> 5;
                const int jl = jr & 31;
                lc[(size_t)((jl >> 2) * 128 + bc) * 16 + (jl & 3) * 4 + g] =
                    (_Float16)acc[mf][nf][i];
            }
    __syncthreads();
    _Float16* dst = XW + ((size_t)t * 256 + (j0 >> 2)) * 2048;
    #pragma unroll
    for (int q = 0; q < 8; ++q) {
        const int off = (q * 256 + tid) * 8;
        *(u16x8*)(dst + off) = *(const u16x8*)(lc + off);
    }
}

__global__ __launch_bounds__(256, 2) void xw_tile_kernel(
    const void* x, const void* W, const void* Wi, const void* Wf, const void* Wo,
    const int* __restrict__ flag, _Float16* XW)
{
    __shared__ unsigned short smem[16384];   // 32 KB
    const int blk = blockIdx.x;        // 24*32 = 768
    const int t   = blk >> 5;
    const int j0  = (blk & 31) * 32;
    if (*flag) xw_tile_body<1>(x, W, Wi, Wf, Wo, XW, t, j0, smem);
    else       xw_tile_body<0>(x, W, Wi, Wf, Wo, XW, t, j0, smem);
}

// ---------------------------------------------------------------------------
// Persistent step kernel v3: grid 272 x 512 thr (R10 step5's proven 8-wave
// geometry), internal loop t=0..24, two-level barrier, double-buffered W.
// ---------------------------------------------------------------------------
// stage 16 W rows (K=1024) -> one 32 KB LDS half, XOR swizzle. 512-thread
// layout (R10-verified): srow = tid>>5 (0..15), scl = (tid&31)*4, 8x stride-128.
template<int FP32>
__device__ __forceinline__ void stage16(
    const void* __restrict__ wptr, size_t woff, int srow, int scl,
    unsigned short* __restrict__ dsthalf)
{
    const unsigned swz = (unsigned)((srow & 7) << 4);
    u16x4 v[8];
    #pragma unroll
    for (int i = 0; i < 8; ++i)
        v[i] = ldcvt4<FP32>(wptr, woff + scl + i * 128);
    #pragma unroll
    for (int i = 0; i < 8; ++i) {
        const int col = scl + i * 128;
        *(u16x4*)((char*)dsthalf + srow * 2048 + (((unsigned)(col * 2)) ^ swz)) = v[i];
    }
}

template<int FP32>
__device__ __forceinline__ void persist_body(
    const void* __restrict__ W,  const void* __restrict__ Wi,
    const void* __restrict__ Wf, const void* __restrict__ Wo,
    const void* __restrict__ bz, const void* __restrict__ bi,
    const void* __restrict__ bfg, const void* __restrict__ bo,
    const void* __restrict__ Wout, const void* __restrict__ bout,
    const _Float16* __restrict__ XW, float* __restrict__ c,
    unsigned short* __restrict__ hA, unsigned short* __restrict__ hB,
    float* __restrict__ out, int* __restrict__ bar,
    unsigned short* __restrict__ smem)   // 64 KB: two 32 KB tile halves
{
    const int blk  = blockIdx.x;
    const int tid  = threadIdx.x;
    const int lane = tid & 63;
    const int wv   = tid >> 6;          // 0..7
    const int c16  = lane & 15;
    const int kg   = lane >> 4;
    const bool isOut = (blk >= G_BLOCKS);

    const int srow = tid >> 5;          // 0..15
    const int scl  = (tid & 31) * 4;
    const unsigned cswz = (unsigned)((c16 & 7) << 4);

    const void* gwptr = nullptr;
    if (!isOut) {
        const int g = srow >> 2;
        gwptr = (g == 0) ? W : (g == 1) ? Wi : (g == 2) ? Wf : Wo;
    }

    // prologue prefetch into half 0
    if (!isOut)
        stage16<FP32>(gwptr, ((size_t)(blk * 4 + (srow & 3))) * IH + INL, srow, scl, smem);
    else
        stage16<FP32>(Wout, ((size_t)((blk - G_BLOCKS) * 16 + srow)) * HL, srow, scl, smem);

    for (int t = 0; t <= NSTEP; ++t) {
        const unsigned short* hp = (t & 1) ? hB : hA;
        unsigned short*       hn = (t & 1) ? hA : hB;

        if (!isOut) {
            if (t < NSTEP) {
                unsigned short* half = smem + (t & 1) * 16384;
                __syncthreads();

                // MFMA: wave wv = rows [wv*16, wv*16+16) x 16 cols, K=1024
                const int row = wv * 16 + c16;
                const char* brow = (const char*)half + c16 * 2048;
                f32x4 acc = {0.f, 0.f, 0.f, 0.f};
                #pragma unroll 8
                for (int kb = 0; kb < HL; kb += 32) {
                    s16x8 av = ldh8(hp, row, kb + kg * 8);
                    s16x8 bv = *(const s16x8*)(brow + (((unsigned)((kb + kg * 8) * 2)) ^ cswz));
                    acc = __builtin_amdgcn_mfma_f32_16x16x32_bf16(av, bv, acc, 0, 0, 0);
                }

                __syncthreads();                    // waves done reading tile
                float* lsm = (float*)half;          // [16 cols][130 rows]
                #pragma unroll
                for (int i = 0; i < 4; ++i)
                    lsm[c16 * 130 + wv * 16 + kg * 4 + i] = acc[i];
                __syncthreads();

                // cell update: tid = b*4 + jq (R10-verified)
                const int b  = tid >> 2;
                const int jq = tid & 3;
                const int jg = blk * 4 + jq;
                u16x4 xv = *(const u16x4*)((const unsigned short*)XW +
                           (((size_t)t * 256 + blk) * B_ + b) * 16 + jq * 4);
                union { unsigned short u; _Float16 h; } x0, x1, x2, x3;
                x0.u = xv[0]; x1.u = xv[1]; x2.u = xv[2]; x3.u = xv[3];
                const float l0 = lsm[(0 * 4 + jq) * 130 + b] + (float)x0.h
                               + ld1<FP32>(bz,  (size_t)t * CL + jg);
                const float l1 = lsm[(1 * 4 + jq) * 130 + b] + (float)x1.h
                               + ld1<FP32>(bi,  (size_t)t * CL + jg);
                const float l2 = lsm[(2 * 4 + jq) * 130 + b] + (float)x2.h
                               + ld1<FP32>(bfg, (size_t)t * CL + jg);
                const float l3 = lsm[(3 * 4 + jq) * 130 + b] + (float)x3.h
                               + ld1<FP32>(bo,  (size_t)t * CL + jg);
                const float z  = tanhf(sane(l0, 30.f));
                const float zi = sigmoidf_(sane(l1, 30.f));
                const float zf = sigmoidf_(sane(l2, 30.f));
                const float zo = sigmoidf_(sane(l3, 30.f));
                const size_t soff = (size_t)blk * 512 + tid;
                const float cold = c[soff];
                const float cn   = sane(zf * cold + zi * z, 50.f);
                c[soff] = cn;
                hn[soff] = f2bf(zo * tanhf(cn));

                // prefetch W(t+1) into the other half (no h dependency)
                if (t + 1 < NSTEP)
                    stage16<FP32>(gwptr,
                        ((size_t)((t + 1) * CL + blk * 4 + (srow & 3))) * IH + INL,
                        srow, scl, smem + ((t + 1) & 1) * 16384);
            }
        } else {
            if (t >= 1) {
                const int tp   = t - 1;
                const int oblk = blk - G_BLOCKS;
                unsigned short* half = smem + (tp & 1) * 16384;
                __syncthreads();

                const int row = wv * 16 + c16;
                const char* brow = (const char*)half + c16 * 2048;
                f32x4 acc = {0.f, 0.f, 0.f, 0.f};
                #pragma unroll 8
                for (int kb = 0; kb < HL; kb += 32) {
                    s16x8 av = ldh8(hp, row, kb + kg * 8);
                    s16x8 bv = *(const s16x8*)(brow + (((unsigned)((kb + kg * 8) * 2)) ^ cswz));
                    acc = __builtin_amdgcn_mfma_f32_16x16x32_bf16(av, bv, acc, 0, 0, 0);
                }
                const int o = oblk * 16 + c16;
                const float bb = ld1<FP32>(bout, (size_t)tp * OUTL + o);
                #pragma unroll
                for (int i = 0; i < 4; ++i) {
                    const int b0 = wv * 16 + kg * 4 + i;
                    out[(size_t)b0 * (NSTEP * OUTL) + (size_t)tp * OUTL + o] =
                        sigmoidf_(sane(acc[i] + bb, 30.f));
                }
                __syncthreads();   // all waves done reading before refill
                if (tp + 1 < NSTEP)
                    stage16<FP32>(Wout,
                        ((size_t)((tp + 1) * OUTL + oblk * 16 + srow)) * HL,
                        srow, scl, smem + ((tp + 1) & 1) * 16384);
            }
        }

        if (t < NSTEP) grid_barrier2(bar + t * 288, blk, tid);
    }
}

__global__ __launch_bounds__(512, 4) void lstm_persist_kernel(
    const void* W, const void* Wi, const void* Wf, const void* Wo,
    const void* bz, const void* bi, const void* bfg, const void* bo,
    const void* Wout, const void* bout,
    const int* __restrict__ flag, const _Float16* XW, float* c,
    unsigned short* hA, unsigned short* hB, float* out, int* bar)
{
    __shared__ unsigned short smem[32768];   // 64 KB (two tile halves)
    if (*flag) persist_body<1>(W, Wi, Wf, Wo, bz, bi, bfg, bo, Wout, bout, XW, c, hA, hB, out, bar, smem);
    else       persist_body<0>(W, Wi, Wf, Wo, bz, bi, bfg, bo, Wout, bout, XW, c, hA, hB, out, bar, smem);
}

// ===========================================================================
// FALLBACK PATH (R5 verbatim, proven)
// ===========================================================================
template<int FP32>
__device__ __forceinline__ void gate_body(
    const void* __restrict__ x,
    const void* __restrict__ W,  const void* __restrict__ Wi,
    const void* __restrict__ Wf, const void* __restrict__ Wo,
    const void* __restrict__ bz, const void* __restrict__ bi,
    const void* __restrict__ bfg, const void* __restrict__ bo,
    _Float16* __restrict__ c,
    const unsigned short* __restrict__ hprev,
    unsigned short* __restrict__ hnext, int t)
{
    const int tid  = threadIdx.x;
    const int lane = tid & 63;
    const int wv   = tid >> 6;
    const int j0   = blockIdx.x * 4;
    const int c16  = lane & 15;
    const int g    = c16 >> 2;
    const int jj   = c16 & 3;
    const int kg   = lane >> 4;

    const void* Wg = (g == 0) ? W : (g == 1) ? Wi : (g == 2) ? Wf : Wo;
    const size_t woff = ((size_t)t * CL + (j0 + jj)) * IH + kg * 8;
    const int row0 = wv * 32 + c16;
    const int row1 = row0 + 16;

    f32x4 acc0 = {0.f, 0.f, 0.f, 0.f};
    f32x4 acc1 = {0.f, 0.f, 0.f, 0.f};
    {
        const size_t a0 = ((size_t)row0 * NSTEP + t) * INL + kg * 8;
        const size_t a1 = ((size_t)row1 * NSTEP + t) * INL + kg * 8;
        #pragma unroll 4
        for (int kb = 0; kb < INL; kb += 32) {
            s16x8 av0 = load8<FP32>(x, a0 + kb);
            s16x8 av1 = load8<FP32>(x, a1 + kb);
            s16x8 bv  = load8<FP32>(Wg, woff + kb);
            acc0 = __builtin_amdgcn_mfma_f32_16x16x32_bf16(av0, bv, acc0, 0, 0, 0);
            acc1 = __builtin_amdgcn_mfma_f32_16x16x32_bf16(av1, bv, acc1, 0, 0, 0);
        }
    }
    {
        const unsigned short* a0 = hprev + (size_t)row0 * HL + kg * 8;
        const unsigned short* a1 = hprev + (size_t)row1 * HL + kg * 8;
        const size_t w2 = woff + INL;
        #pragma unroll 4
        for (int kb = 0; kb < HL; kb += 32) {
            s16x8 av0 = *(const s16x8*)(a0 + kb);
            s16x8 av1 = *(const s16x8*)(a1 + kb);
            s16x8 bv  = load8<FP32>(Wg, w2 + kb);
            acc0 = __builtin_amdgcn_mfma_f32_16x16x32_bf16(av0, bv, acc0, 0, 0, 0);
            acc1 = __builtin_amdgcn_mfma_f32_16x16x32_bf16(av1, bv, acc1, 0, 0, 0);
        }
    }
    __shared__ float lg[4][4][B_];
    #pragma unroll
    for (int i = 0; i < 4; ++i) {
        lg[g][jj][wv * 32 + kg * 4 + i]      = acc0[i];
        lg[g][jj][wv * 32 + 16 + kg * 4 + i] = acc1[i];
    }
    __syncthreads();
    #pragma unroll
    for (int p = 0; p < 2; ++p) {
        const int idx = tid + p * 256;
        const int b   = idx & 127;
        const int jl  = idx >> 7;
        const int jg  = j0 + jl;
        const float z  = tanhf   (sane(lg[0][jl][b] + ld1<FP32>(bz,  t * CL + jg), 30.f));
        const float zi = sigmoidf_(sane(lg[1][jl][b] + ld1<FP32>(bi,  t * CL + jg), 30.f));
        const float zf = sigmoidf_(sane(lg[2][jl][b] + ld1<FP32>(bfg, t * CL + jg), 30.f));
        const float zo = sigmoidf_(sane(lg[3][jl][b] + ld1<FP32>(bo,  t * CL + jg), 30.f));
        const float cold = (float)c[(size_t)b * CL + jg];
        const float cn   = sane(zf * cold + zi * z, 50.f);
        c[(size_t)b * CL + jg] = (_Float16)cn;
        hnext[(size_t)b * HL + jg] = f2bf(zo * tanhf(cn));
    }
}

__global__ __launch_bounds__(256, 1) void gate_cell_kernel(
    const void* x, const void* W, const void* Wi, const void* Wf, const void* Wo,
    const void* bz, const void* bi, const void* bfg, const void* bo,
    const int* __restrict__ flag, _Float16* c,
    const unsigned short* hprev, unsigned short* hnext, int t)
{
    if (*flag) gate_body<1>(x, W, Wi, Wf, Wo, bz, bi, bfg, bo, c, hprev, hnext, t);
    else       gate_body<0>(x, W, Wi, Wf, Wo, bz, bi, bfg, bo, c, hprev, hnext, t);
}

template<int FP32>
__device__ __forceinline__ void outproj_body(
    const unsigned short* __restrict__ h, const void* __restrict__ Wout,
    const void* __restrict__ bout, float* __restrict__ out, int t)
{
    const int tid  = threadIdx.x;
    const int lane = tid & 63;
    const int wv   = tid >> 6;
    const int o    = blockIdx.x * 16 + (lane & 15);
    const int kg   = lane >> 4;
    const size_t woff = ((size_t)t * OUTL + o) * HL + kg * 8;
    const int row0 = wv * 32 + (lane & 15);
    const int row1 = row0 + 16;
    const unsigned short* a0 = h + (size_t)row0 * HL + kg * 8;
    const unsigned short* a1 = h + (size_t)row1 * HL + kg * 8;

    f32x4 acc0 = {0.f, 0.f, 0.f, 0.f};
    f32x4 acc1 = {0.f, 0.f, 0.f, 0.f};
    #pragma unroll 4
    for (int kb = 0; kb < HL; kb += 32) {
        s16x8 av0 = *(const s16x8*)(a0 + kb);
        s16x8 av1 = *(const s16x8*)(a1 + kb);
        s16x8 bv  = load8<FP32>(Wout, woff + kb);
        acc0 = __builtin_amdgcn_mfma_f32_16x16x32_bf16(av0, bv, acc0, 0, 0, 0);
        acc1 = __builtin_amdgcn_mfma_f32_16x16x32_bf16(av1, bv, acc1, 0, 0, 0);
    }
    const float bb = ld1<FP32>(bout, (size_t)t * OUTL + o);
    #pragma unroll
    for (int i = 0; i < 4; ++i) {
        const int r0 = wv * 32 + kg * 4 + i;
        out[(size_t)r0 * (NSTEP * OUTL) + (size_t)t * OUTL + o] =
            sigmoidf_(sane(acc0[i] + bb, 30.f));
        out[(size_t)(r0 + 16) * (NSTEP * OUTL) + (size_t)t * OUTL + o] =
            sigmoidf_(sane(acc1[i] + bb, 30.f));
    }
}

__global__ __launch_bounds__(256, 1) void outproj_kernel(
    const unsigned short* h, const void* Wout, const void* bout,
    const int* __restrict__ flag, float* out, int t)
{
    if (*flag) outproj_body<1>(h, Wout, bout, out, t);
    else       outproj_body<0>(h, Wout, bout, out, t);
}

__global__ void init_kernel(const void* c0, const void* h0, const int* __restrict__ flag,
                            _Float16* __restrict__ c,
                            unsigned short* __restrict__ hA,
                            unsigned short* __restrict__ hB)
{
    const int f   = *flag;
    const int idx = blockIdx.x * blockDim.x + threadIdx.x;
    if (idx < B_ * CL) {
        const int j = idx & (CL - 1);
        const float cv = f ? ((const float*)c0)[j] : bits2f(((const unsigned short*)c0)[j]);
        const float hv = f ? ((const float*)h0)[j] : bits2f(((const unsigned short*)h0)[j]);
        c[idx]  = (_Float16)cv;
        const unsigned short hb = f2bf(hv);
        hA[idx] = hb;
        hB[idx] = hb;
    }
}

// ===========================================================================
extern "C" void kernel_launch(void* const* d_in, const int* in_sizes, int n_in,
                              void* d_out, int out_size, void* d_ws, size_t ws_size,
                              hipStream_t stream)
{
    const void* x    = d_in[0];
    const void* W    = d_in[1];
    const void* Wi   = d_in[2];
    const void* Wf   = d_in[3];
    const void* Wo   = d_in[4];
    const void* Wout = d_in[5];
    const void* bz   = d_in[6];
    const void* bi   = d_in[7];
    const void* bfg  = d_in[8];
    const void* bo   = d_in[9];
    const void* bout = d_in[10];
    const void* c0   = d_in[11];
    const void* h0   = d_in[12];

    char* ws  = (char*)d_ws;
    int* flag = (int*)ws;
    float* out = (float*)d_out;   // OUTPUT IS FP32 (R4/R5 evidence)

    detect_kernel<<<1, 256, 0, stream>>>((const unsigned*)x, flag);

    if (ws_size >= (size_t)FWS_END) {
        float*          c   = (float*)(ws + FWS_C);
        unsigned short* hA  = (unsigned short*)(ws + FWS_HA);
        unsigned short* hB  = (unsigned short*)(ws + FWS_HB);
        int*            bar = (int*)(ws + FWS_BAR);
        _Float16*       XW  = (_Float16*)(ws + FWS_XW);

        init_full_kernel<<<512, 256, 0, stream>>>(c0, h0, flag, c, hA, hB, bar);
        xw_tile_kernel<<<768, 256, 0, stream>>>(x, W, Wi, Wf, Wo, flag, XW);
        lstm_persist_kernel<<<NBLK, 512, 0, stream>>>(
            W, Wi, Wf, Wo, bz, bi, bfg, bo, Wout, bout,
            flag, XW, c, hA, hB, out, bar);
    } else {
        _Float16*       c  = (_Float16*)(ws + WS_C);
        unsigned short* hA = (unsigned short*)(ws + WS_HA);
        unsigned short* hB = (unsigned short*)(ws + WS_HB);

        init_kernel<<<512, 256, 0, stream>>>(c0, h0, flag, c, hA, hB);
        for (int t = 0; t < NSTEP; ++t) {
            const unsigned short* hp = (t & 1) ? hB : hA;
            unsigned short*       hn = (t & 1) ? hA : hB;
            gate_cell_kernel<<<256, 256, 0, stream>>>(
                x, W, Wi, Wf, Wo, bz, bi, bfg, bo, flag, c, hp, hn, t);
            outproj_kernel<<<16, 256, 0, stream>>>(hn, Wout, bout, flag, out, t);
        }
    }
}

// Round 15
// 421.097 us; speedup vs baseline: 3.2488x; 3.2488x over previous
//
#include <hip/hip_runtime.h>

#define B_    128
#define NSTEP 24
#define INL   512
#define OUTL  256
#define HL    1024
#define CL    1024
#define IH    (INL + HL)   // 1536
#define G_BLOCKS 256       // gate blocks per step (4 j-cols x 4 gates = 16 rows)

typedef short          s16x8 __attribute__((ext_vector_type(8)));
typedef float          f32x4 __attribute__((ext_vector_type(4)));
typedef unsigned short u16x4 __attribute__((ext_vector_type(4)));
typedef unsigned short u16x8 __attribute__((ext_vector_type(8)));

// ---------- full-path ws layout ----------
// h, c BLOCK-MAJOR: off(b,j) = (j>>2)*512 + b*4 + (j&3)
// XW fp16: ((t*256 + jblk)*128 + b)*16 + jj*4 + g
#define FWS_C   64
#define FWS_HA  (FWS_C + 524288)
#define FWS_HB  (FWS_HA + 262144)
#define FWS_XW  (FWS_HB + 262144)
#define FWS_END (FWS_XW + 25165824)
// ---------- fallback (R5, proven) ----------
#define WS_C  64
#define WS_HA (64 + 262144)
#define WS_HB (64 + 524288)

__device__ __forceinline__ float bits2f(unsigned short u) {
    union { unsigned u; float f; } w; w.u = ((unsigned)u) << 16; return w.f;
}
__device__ __forceinline__ unsigned short f2bf(float f) {
    union { float f; unsigned u; } w; w.f = f;
    unsigned r = (w.u + 0x7fffu + ((w.u >> 16) & 1u)) >> 16;   // RNE
    return (unsigned short)r;
}
__device__ __forceinline__ float sigmoidf_(float v) { return 1.0f / (1.0f + expf(-v)); }
__device__ __forceinline__ float sane(float v, float lim) {   // NaN -> bounded
    return fminf(fmaxf(v, -lim), lim);
}

template<int FP32>
__device__ __forceinline__ s16x8 load8(const void* base, size_t off) {
    if constexpr (FP32) {
        const float* p = (const float*)base + off;
        f32x4 a = *(const f32x4*)p;
        f32x4 b = *(const f32x4*)(p + 4);
        s16x8 r;
        r[0] = (short)f2bf(a[0]); r[1] = (short)f2bf(a[1]);
        r[2] = (short)f2bf(a[2]); r[3] = (short)f2bf(a[3]);
        r[4] = (short)f2bf(b[0]); r[5] = (short)f2bf(b[1]);
        r[6] = (short)f2bf(b[2]); r[7] = (short)f2bf(b[3]);
        return r;
    } else {
        return *(const s16x8*)((const unsigned short*)base + off);
    }
}
template<int FP32>
__device__ __forceinline__ float ld1(const void* base, size_t off) {
    if constexpr (FP32) return ((const float*)base)[off];
    else                return bits2f(((const unsigned short*)base)[off]);
}
template<int FP32>
__device__ __forceinline__ u16x4 ldcvt4(const void* base, size_t off) {
    if constexpr (FP32) {
        f32x4 v = *(const f32x4*)((const float*)base + off);
        u16x4 r;
        r[0] = f2bf(v[0]); r[1] = f2bf(v[1]); r[2] = f2bf(v[2]); r[3] = f2bf(v[3]);
        return r;
    } else {
        return *(const u16x4*)((const unsigned short*)base + off);
    }
}
// A-fragment (8 k-elems) from block-major h; k0 multiple of 8
__device__ __forceinline__ s16x8 ldh8(const unsigned short* __restrict__ h,
                                      int row, int k0) {
    const unsigned short* p = h + (size_t)(k0 >> 2) * 512 + row * 4;
    u16x4 lo = *(const u16x4*)p;
    u16x4 hi = *(const u16x4*)(p + 512);
    s16x8 r;
    r[0] = (short)lo[0]; r[1] = (short)lo[1]; r[2] = (short)lo[2]; r[3] = (short)lo[3];
    r[4] = (short)hi[0]; r[5] = (short)hi[1]; r[6] = (short)hi[2]; r[7] = (short)hi[3];
    return r;
}

// ---------------------------------------------------------------------------
// Dtype detector (verified flag=1/fp32 on this harness in R4).
// ---------------------------------------------------------------------------
__global__ void detect_kernel(const unsigned* __restrict__ xw, int* __restrict__ flag) {
    __shared__ int wild, zero;
    const int tid = threadIdx.x;
    if (tid == 0) { wild = 0; zero = 0; }
    __syncthreads();
    int w = 0, z = 0;
    for (int s = 0; s < 4; ++s) {
        unsigned short lo = (unsigned short)(xw[tid * 4 + s] & 0xffffu);
        float v = bits2f(lo);
        if (v == 0.0f) z++;
        else if (v == v && (fabsf(v) > 1e4f || fabsf(v) < 1e-8f)) w++;
    }
    atomicAdd(&wild, w);
    atomicAdd(&zero, z);
    __syncthreads();
    if (tid == 0) *flag = (wild > 128 || zero > 512) ? 1 : 0;
}

// ===========================================================================
// FULL PATH  (R10 multi-launch structure, 438 µs proven; persistent-kernel
// variants measured worse 3x (R12 1914, R13 971, R14 1368) -> abandoned.)
// ===========================================================================

// init block-major c/h: linear idx == block-major offset; j = (idx>>9)*4 + (idx&3)
__global__ void init_full_kernel(const void* c0, const void* h0, const int* __restrict__ flag,
                                 float* __restrict__ c,
                                 unsigned short* __restrict__ hA,
                                 unsigned short* __restrict__ hB)
{
    const int f   = *flag;
    const int idx = blockIdx.x * blockDim.x + threadIdx.x;
    if (idx < B_ * CL) {
        const int j = ((idx >> 9) << 2) + (idx & 3);
        c[idx]  = f ? ((const float*)c0)[j] : bits2f(((const unsigned short*)c0)[j]);
        const float hv = f ? ((const float*)h0)[j] : bits2f(((const unsigned short*)h0)[j]);
        const unsigned short hb = f2bf(hv);
        hA[idx] = hb;
        hB[idx] = hb;
    }
}

// ---------------------------------------------------------------------------
// XW tile GEMM — R10 math + R12 epilogue (LDS-staged C, contiguous u16x8
// stores; ran correct in R12/13/14). (256,2) config per R7/R8 evidence.
// ---------------------------------------------------------------------------
#define XA_PITCH 40
template<int FP32>
__device__ __forceinline__ void xw_tile_body(
    const void* __restrict__ x,
    const void* __restrict__ W,  const void* __restrict__ Wi,
    const void* __restrict__ Wf, const void* __restrict__ Wo,
    _Float16* __restrict__ XW, int t, int j0,
    unsigned short* __restrict__ smem)
{
    unsigned short* Alds = smem;                   // W rows  [128][40]
    unsigned short* Blds = smem + 128 * XA_PITCH;  // x rows  [128][40]

    const int tid  = threadIdx.x;
    const int lane = tid & 63;
    const int wv   = tid >> 6;
    const int c16  = lane & 15;
    const int kg   = lane >> 4;
    const int mq   = wv >> 1, nq = wv & 1;

    int rowc[4], colc[4];
    const void* wbase[4];
    size_t wrow[4];
    #pragma unroll
    for (int p = 0; p < 4; ++p) {
        const int cid = tid + p * 256;
        rowc[p] = cid >> 3;
        colc[p] = (cid & 7) * 4;
        const int g = rowc[p] >> 5;
        wbase[p] = (g == 0) ? W : (g == 1) ? Wi : (g == 2) ? Wf : Wo;
        wrow[p]  = ((size_t)(t * CL + j0 + (rowc[p] & 31))) * IH;
    }

    f32x4 acc[4][4];
    #pragma unroll
    for (int a = 0; a < 4; ++a)
        #pragma unroll
        for (int b = 0; b < 4; ++b) acc[a][b] = (f32x4){0.f, 0.f, 0.f, 0.f};

    u16x4 ra[4], rb[4];
    #pragma unroll
    for (int p = 0; p < 4; ++p) {
        ra[p] = ldcvt4<FP32>(wbase[p], wrow[p] + colc[p]);
        rb[p] = ldcvt4<FP32>(x,  ((size_t)(rowc[p] * NSTEP + t)) * INL + colc[p]);
    }

    for (int s = 0; s < 16; ++s) {
        __syncthreads();
        #pragma unroll
        for (int p = 0; p < 4; ++p) {
            *(u16x4*)(Alds + rowc[p] * XA_PITCH + colc[p]) = ra[p];
            *(u16x4*)(Blds + rowc[p] * XA_PITCH + colc[p]) = rb[p];
        }
        if (s < 15) {
            const int k0 = (s + 1) * 32;
            #pragma unroll
            for (int p = 0; p < 4; ++p) {
                ra[p] = ldcvt4<FP32>(wbase[p], wrow[p] + k0 + colc[p]);
                rb[p] = ldcvt4<FP32>(x,  ((size_t)(rowc[p] * NSTEP + t)) * INL + k0 + colc[p]);
            }
        }
        __syncthreads();
        s16x8 av[4], bv[4];
        #pragma unroll
        for (int mf = 0; mf < 4; ++mf)
            av[mf] = *(const s16x8*)(Alds + (mq * 64 + mf * 16 + c16) * XA_PITCH + kg * 8);
        #pragma unroll
        for (int nf = 0; nf < 4; ++nf)
            bv[nf] = *(const s16x8*)(Blds + (nq * 64 + nf * 16 + c16) * XA_PITCH + kg * 8);
        #pragma unroll
        for (int mf = 0; mf < 4; ++mf)
            #pragma unroll
            for (int nf = 0; nf < 4; ++nf)
                acc[mf][nf] = __builtin_amdgcn_mfma_f32_16x16x32_bf16(av[mf], bv[nf], acc[mf][nf], 0, 0, 0);
    }

    // C-stage via LDS, then contiguous 16B copy-out (R12 epilogue)
    __syncthreads();
    _Float16* lc = (_Float16*)smem;   // [8 jblkL][128 b][4 jj][4 g] = 32 KB
    #pragma unroll
    for (int mf = 0; mf < 4; ++mf)
        #pragma unroll
        for (int nf = 0; nf < 4; ++nf)
            #pragma unroll
            for (int i = 0; i < 4; ++i) {
                const int jr = mq * 64 + mf * 16 + kg * 4 + i;   // 0..127
                const int bc = nq * 64 + nf * 16 + c16;
                const int g  = jr >> 5;
                const int jl = jr & 31;
                lc[(size_t)((jl >> 2) * 128 + bc) * 16 + (jl & 3) * 4 + g] =
                    (_Float16)acc[mf][nf][i];
            }
    __syncthreads();
    _Float16* dst = XW + ((size_t)t * 256 + (j0 >> 2)) * 2048;
    #pragma unroll
    for (int q = 0; q < 8; ++q) {
        const int off = (q * 256 + tid) * 8;
        *(u16x8*)(dst + off) = *(const u16x8*)(lc + off);
    }
}

__global__ __launch_bounds__(256, 2) void xw_tile_kernel(
    const void* x, const void* W, const void* Wi, const void* Wf, const void* Wo,
    const int* __restrict__ flag, _Float16* XW)
{
    __shared__ unsigned short smem[16384];   // 32 KB
    const int blk = blockIdx.x;        // 24*32 = 768
    const int t   = blk >> 5;
    const int j0  = (blk & 31) * 32;
    if (*flag) xw_tile_body<1>(x, W, Wi, Wf, Wo, XW, t, j0, smem);
    else       xw_tile_body<0>(x, W, Wi, Wf, Wo, XW, t, j0, smem);
}

// ---------------------------------------------------------------------------
// step5: grid 272 x 512 thr (R10 verbatim, 13 µs/step proven).
//  blocks 0..255  : gate slice (16 gate-rows = 4 j x 4 gates) + cell update
//  blocks 256..271: outproj(t-1), 16 o-cols each (skip at t=0)
// ---------------------------------------------------------------------------
template<int FP32>
__device__ __forceinline__ void step5_body(
    const void* __restrict__ W,  const void* __restrict__ Wi,
    const void* __restrict__ Wf, const void* __restrict__ Wo,
    const void* __restrict__ bz, const void* __restrict__ bi,
    const void* __restrict__ bfg, const void* __restrict__ bo,
    const void* __restrict__ Wout, const void* __restrict__ bout,
    const _Float16* __restrict__ XW, float* __restrict__ c,
    const unsigned short* __restrict__ hprev,
    unsigned short* __restrict__ hnext,
    float* __restrict__ out, int t)
{
    __shared__ unsigned short smem[16 * 1024];   // 32 KB W tile (XOR-swizzled rows)
    const int blk  = blockIdx.x;
    const int tid  = threadIdx.x;
    const int lane = tid & 63;
    const int wv   = tid >> 6;          // 0..7 -> batch rows [wv*16, wv*16+16)
    const int c16  = lane & 15;
    const int kg   = lane >> 4;
    const bool isOut = (blk >= G_BLOCKS);
    if (isOut && t == 0) return;

    // stage 16 W rows -> LDS bf16, byte ^= (row&7)<<4 swizzle
    {
        const int srow = tid >> 5;            // 0..15
        const int scl  = (tid & 31) * 4;
        const void* wptr;
        size_t woff;
        if (!isOut) {
            const int g = srow >> 2, jj = srow & 3;
            wptr = (g == 0) ? W : (g == 1) ? Wi : (g == 2) ? Wf : Wo;
            woff = ((size_t)(t * CL + blk * 4 + jj)) * IH + INL;
        } else {
            wptr = Wout;
            woff = ((size_t)((t - 1) * OUTL + (blk - G_BLOCKS) * 16 + srow)) * HL;
        }
        const unsigned swz = (unsigned)((srow & 7) << 4);
        #pragma unroll
        for (int i = 0; i < 8; ++i) {
            const int col = scl + i * 128;
            u16x4 v = ldcvt4<FP32>(wptr, woff + col);
            *(u16x4*)((char*)smem + srow * 2048 + (((unsigned)(col * 2)) ^ swz)) = v;
        }
    }
    __syncthreads();

    // MFMA: wave wv = 16 batch rows x block's 16 cols, K = 1024
    const int row = wv * 16 + c16;
    const char* brow = (const char*)smem + c16 * 2048;
    const unsigned cswz = (unsigned)((c16 & 7) << 4);
    f32x4 acc = {0.f, 0.f, 0.f, 0.f};
    #pragma unroll 8
    for (int kb = 0; kb < HL; kb += 32) {
        s16x8 av = ldh8(hprev, row, kb + kg * 8);
        s16x8 bv = *(const s16x8*)(brow + (((unsigned)((kb + kg * 8) * 2)) ^ cswz));
        acc = __builtin_amdgcn_mfma_f32_16x16x32_bf16(av, bv, acc, 0, 0, 0);
    }

    if (isOut) {
        // C/D: row(batch) = wv*16 + kg*4 + i, col = c16
        const int o = (blk - G_BLOCKS) * 16 + c16;
        const float bb = ld1<FP32>(bout, (size_t)(t - 1) * OUTL + o);
        #pragma unroll
        for (int i = 0; i < 4; ++i) {
            const int b = wv * 16 + kg * 4 + i;
            out[(size_t)b * (NSTEP * OUTL) + (size_t)(t - 1) * OUTL + o] =
                sigmoidf_(sane(acc[i] + bb, 30.f));
        }
        return;
    }

    // gate: redistribute logits via LDS (aliases W tile), cell update
    __syncthreads();
    float* lsm = (float*)smem;          // [16 cols][130 rows]
    #pragma unroll
    for (int i = 0; i < 4; ++i)
        lsm[c16 * 130 + wv * 16 + kg * 4 + i] = acc[i];
    __syncthreads();

    // cell update: tid = b*4 + jq -> writes h/c at blk*512 + tid (coalesced)
    const int b  = tid >> 2;
    const int jq = tid & 3;
    const int jg = blk * 4 + jq;
    u16x4 xv = *(const u16x4*)((const unsigned short*)XW +
                               (((size_t)t * 256 + blk) * B_ + b) * 16 + jq * 4);
    union { unsigned short u; _Float16 h; } cv0, cv1, cv2, cv3;
    cv0.u = xv[0]; cv1.u = xv[1]; cv2.u = xv[2]; cv3.u = xv[3];
    const float l0 = lsm[(0 * 4 + jq) * 130 + b] + (float)cv0.h
                   + ld1<FP32>(bz,  (size_t)t * CL + jg);
    const float l1 = lsm[(1 * 4 + jq) * 130 + b] + (float)cv1.h
                   + ld1<FP32>(bi,  (size_t)t * CL + jg);
    const float l2 = lsm[(2 * 4 + jq) * 130 + b] + (float)cv2.h
                   + ld1<FP32>(bfg, (size_t)t * CL + jg);
    const float l3 = lsm[(3 * 4 + jq) * 130 + b] + (float)cv3.h
                   + ld1<FP32>(bo,  (size_t)t * CL + jg);
    const float z  = tanhf(sane(l0, 30.f));
    const float zi = sigmoidf_(sane(l1, 30.f));
    const float zf = sigmoidf_(sane(l2, 30.f));
    const float zo = sigmoidf_(sane(l3, 30.f));
    const size_t soff = (size_t)blk * 512 + tid;
    const float cold = c[soff];
    const float cn   = sane(zf * cold + zi * z, 50.f);
    c[soff] = cn;
    hnext[soff] = f2bf(zo * tanhf(cn));
}

__global__ __launch_bounds__(512, 4) void step5_kernel(
    const void* W, const void* Wi, const void* Wf, const void* Wo,
    const void* bz, const void* bi, const void* bfg, const void* bo,
    const void* Wout, const void* bout,
    const int* __restrict__ flag, const _Float16* XW, float* c,
    const unsigned short* hprev, unsigned short* hnext, float* out, int t)
{
    if (*flag) step5_body<1>(W, Wi, Wf, Wo, bz, bi, bfg, bo, Wout, bout, XW, c, hprev, hnext, out, t);
    else       step5_body<0>(W, Wi, Wf, Wo, bz, bi, bfg, bo, Wout, bout, XW, c, hprev, hnext, out, t);
}

// ---------------------------------------------------------------------------
// Outproj quarter-tile (R10 verbatim; block-major h A-loads).
// ---------------------------------------------------------------------------
template<int FP32>
__device__ __forceinline__ void outproj_part(
    const unsigned short* __restrict__ h, const void* __restrict__ Wout,
    const void* __restrict__ bout, float* __restrict__ out, int tp, int og,
    int tid, float* __restrict__ red)
{
    const int lane = tid & 63;
    const int wv   = tid >> 6;          // 0..3
    const int c16  = lane & 15;
    const int kg   = lane >> 4;
    const int mf   = wv & 1;
    const int kh   = wv >> 1;

    const int o0   = (og & 15) * 16;
    const int mgrp = og >> 4;
    const int o    = o0 + c16;

    const size_t woff = ((size_t)tp * OUTL + o) * HL + kh * 512 + kg * 8;
    const int row = mgrp * 32 + mf * 16 + c16;

    f32x4 acc = {0.f, 0.f, 0.f, 0.f};
    #pragma unroll 8
    for (int kb = 0; kb < 512; kb += 32) {
        s16x8 av = ldh8(h, row, kh * 512 + kb + kg * 8);
        s16x8 bv = load8<FP32>(Wout, woff + kb);
        acc = __builtin_amdgcn_mfma_f32_16x16x32_bf16(av, bv, acc, 0, 0, 0);
    }
    #pragma unroll
    for (int i = 0; i < 4; ++i)
        red[((kh * 2 + mf) * 16 + c16) * 16 + kg * 4 + i] = acc[i];
    __syncthreads();

    const float bb = ld1<FP32>(bout, (size_t)tp * OUTL + o0 + (tid & 15));
    #pragma unroll
    for (int p = 0; p < 2; ++p) {
        const int idx = tid + p * 256;
        const int cc  = idx & 15;
        const int r   = idx >> 4;
        const int mff = r >> 4, rm = r & 15;
        const float lgv = red[(mff * 16 + cc) * 16 + rm]
                        + red[((2 + mff) * 16 + cc) * 16 + rm] + bb;
        out[(size_t)(mgrp * 32 + r) * (NSTEP * OUTL) + (size_t)tp * OUTL + o0 + cc] =
            sigmoidf_(sane(lgv, 30.f));
    }
}

__global__ __launch_bounds__(512, 4) void outproj_final2_kernel(
    const unsigned short* h, const void* Wout, const void* bout,
    const int* __restrict__ flag, float* out)
{
    __shared__ float red[2048];
    const int tid  = threadIdx.x;
    const int half = tid >> 8;
    const int og   = blockIdx.x * 2 + half;
    if (*flag) outproj_part<1>(h, Wout, bout, out, NSTEP - 1, og, tid & 255, red + half * 1024);
    else       outproj_part<0>(h, Wout, bout, out, NSTEP - 1, og, tid & 255, red + half * 1024);
}

// ===========================================================================
// FALLBACK PATH (R5 verbatim, proven)
// ===========================================================================
template<int FP32>
__device__ __forceinline__ void gate_body(
    const void* __restrict__ x,
    const void* __restrict__ W,  const void* __restrict__ Wi,
    const void* __restrict__ Wf, const void* __restrict__ Wo,
    const void* __restrict__ bz, const void* __restrict__ bi,
    const void* __restrict__ bfg, const void* __restrict__ bo,
    _Float16* __restrict__ c,
    const unsigned short* __restrict__ hprev,
    unsigned short* __restrict__ hnext, int t)
{
    const int tid  = threadIdx.x;
    const int lane = tid & 63;
    const int wv   = tid >> 6;
    const int j0   = blockIdx.x * 4;
    const int c16  = lane & 15;
    const int g    = c16 >> 2;
    const int jj   = c16 & 3;
    const int kg   = lane >> 4;

    const void* Wg = (g == 0) ? W : (g == 1) ? Wi : (g == 2) ? Wf : Wo;
    const size_t woff = ((size_t)t * CL + (j0 + jj)) * IH + kg * 8;
    const int row0 = wv * 32 + c16;
    const int row1 = row0 + 16;

    f32x4 acc0 = {0.f, 0.f, 0.f, 0.f};
    f32x4 acc1 = {0.f, 0.f, 0.f, 0.f};
    {
        const size_t a0 = ((size_t)row0 * NSTEP + t) * INL + kg * 8;
        const size_t a1 = ((size_t)row1 * NSTEP + t) * INL + kg * 8;
        #pragma unroll 4
        for (int kb = 0; kb < INL; kb += 32) {
            s16x8 av0 = load8<FP32>(x, a0 + kb);
            s16x8 av1 = load8<FP32>(x, a1 + kb);
            s16x8 bv  = load8<FP32>(Wg, woff + kb);
            acc0 = __builtin_amdgcn_mfma_f32_16x16x32_bf16(av0, bv, acc0, 0, 0, 0);
            acc1 = __builtin_amdgcn_mfma_f32_16x16x32_bf16(av1, bv, acc1, 0, 0, 0);
        }
    }
    {
        const unsigned short* a0 = hprev + (size_t)row0 * HL + kg * 8;
        const unsigned short* a1 = hprev + (size_t)row1 * HL + kg * 8;
        const size_t w2 = woff + INL;
        #pragma unroll 4
        for (int kb = 0; kb < HL; kb += 32) {
            s16x8 av0 = *(const s16x8*)(a0 + kb);
            s16x8 av1 = *(const s16x8*)(a1 + kb);
            s16x8 bv  = load8<FP32>(Wg, w2 + kb);
            acc0 = __builtin_amdgcn_mfma_f32_16x16x32_bf16(av0, bv, acc0, 0, 0, 0);
            acc1 = __builtin_amdgcn_mfma_f32_16x16x32_bf16(av1, bv, acc1, 0, 0, 0);
        }
    }
    __shared__ float lg[4][4][B_];
    #pragma unroll
    for (int i = 0; i < 4; ++i) {
        lg[g][jj][wv * 32 + kg * 4 + i]      = acc0[i];
        lg[g][jj][wv * 32 + 16 + kg * 4 + i] = acc1[i];
    }
    __syncthreads();
    #pragma unroll
    for (int p = 0; p < 2; ++p) {
        const int idx = tid + p * 256;
        const int b   = idx & 127;
        const int jl  = idx >> 7;
        const int jg  = j0 + jl;
        const float z  = tanhf   (sane(lg[0][jl][b] + ld1<FP32>(bz,  t * CL + jg), 30.f));
        const float zi = sigmoidf_(sane(lg[1][jl][b] + ld1<FP32>(bi,  t * CL + jg), 30.f));
        const float zf = sigmoidf_(sane(lg[2][jl][b] + ld1<FP32>(bfg, t * CL + jg), 30.f));
        const float zo = sigmoidf_(sane(lg[3][jl][b] + ld1<FP32>(bo,  t * CL + jg), 30.f));
        const float cold = (float)c[(size_t)b * CL + jg];
        const float cn   = sane(zf * cold + zi * z, 50.f);
        c[(size_t)b * CL + jg] = (_Float16)cn;
        hnext[(size_t)b * HL + jg] = f2bf(zo * tanhf(cn));
    }
}

__global__ __launch_bounds__(256, 1) void gate_cell_kernel(
    const void* x, const void* W, const void* Wi, const void* Wf, const void* Wo,
    const void* bz, const void* bi, const void* bfg, const void* bo,
    const int* __restrict__ flag, _Float16* c,
    const unsigned short* hprev, unsigned short* hnext, int t)
{
    if (*flag) gate_body<1>(x, W, Wi, Wf, Wo, bz, bi, bfg, bo, c, hprev, hnext, t);
    else       gate_body<0>(x, W, Wi, Wf, Wo, bz, bi, bfg, bo, c, hprev, hnext, t);
}

template<int FP32>
__device__ __forceinline__ void outproj_body(
    const unsigned short* __restrict__ h, const void* __restrict__ Wout,
    const void* __restrict__ bout, float* __restrict__ out, int t)
{
    const int tid  = threadIdx.x;
    const int lane = tid & 63;
    const int wv   = tid >> 6;
    const int o    = blockIdx.x * 16 + (lane & 15);
    const int kg   = lane >> 4;
    const size_t woff = ((size_t)t * OUTL + o) * HL + kg * 8;
    const int row0 = wv * 32 + (lane & 15);
    const int row1 = row0 + 16;
    const unsigned short* a0 = h + (size_t)row0 * HL + kg * 8;
    const unsigned short* a1 = h + (size_t)row1 * HL + kg * 8;

    f32x4 acc0 = {0.f, 0.f, 0.f, 0.f};
    f32x4 acc1 = {0.f, 0.f, 0.f, 0.f};
    #pragma unroll 4
    for (int kb = 0; kb < HL; kb += 32) {
        s16x8 av0 = *(const s16x8*)(a0 + kb);
        s16x8 av1 = *(const s16x8*)(a1 + kb);
        s16x8 bv  = load8<FP32>(Wout, woff + kb);
        acc0 = __builtin_amdgcn_mfma_f32_16x16x32_bf16(av0, bv, acc0, 0, 0, 0);
        acc1 = __builtin_amdgcn_mfma_f32_16x16x32_bf16(av1, bv, acc1, 0, 0, 0);
    }
    const float bb = ld1<FP32>(bout, (size_t)t * OUTL + o);
    #pragma unroll
    for (int i = 0; i < 4; ++i) {
        const int r0 = wv * 32 + kg * 4 + i;
        out[(size_t)r0 * (NSTEP * OUTL) + (size_t)t * OUTL + o] =
            sigmoidf_(sane(acc0[i] + bb, 30.f));
        out[(size_t)(r0 + 16) * (NSTEP * OUTL) + (size_t)t * OUTL + o] =
            sigmoidf_(sane(acc1[i] + bb, 30.f));
    }
}

__global__ __launch_bounds__(256, 1) void outproj_kernel(
    const unsigned short* h, const void* Wout, const void* bout,
    const int* __restrict__ flag, float* out, int t)
{
    if (*flag) outproj_body<1>(h, Wout, bout, out, t);
    else       outproj_body<0>(h, Wout, bout, out, t);
}

__global__ void init_kernel(const void* c0, const void* h0, const int* __restrict__ flag,
                            _Float16* __restrict__ c,
                            unsigned short* __restrict__ hA,
                            unsigned short* __restrict__ hB)
{
    const int f   = *flag;
    const int idx = blockIdx.x * blockDim.x + threadIdx.x;
    if (idx < B_ * CL) {
        const int j = idx & (CL - 1);
        const float cv = f ? ((const float*)c0)[j] : bits2f(((const unsigned short*)c0)[j]);
        const float hv = f ? ((const float*)h0)[j] : bits2f(((const unsigned short*)h0)[j]);
        c[idx]  = (_Float16)cv;
        const unsigned short hb = f2bf(hv);
        hA[idx] = hb;
        hB[idx] = hb;
    }
}

// ===========================================================================
extern "C" void kernel_launch(void* const* d_in, const int* in_sizes, int n_in,
                              void* d_out, int out_size, void* d_ws, size_t ws_size,
                              hipStream_t stream)
{
    const void* x    = d_in[0];
    const void* W    = d_in[1];
    const void* Wi   = d_in[2];
    const void* Wf   = d_in[3];
    const void* Wo   = d_in[4];
    const void* Wout = d_in[5];
    const void* bz   = d_in[6];
    const void* bi   = d_in[7];
    const void* bfg  = d_in[8];
    const void* bo   = d_in[9];
    const void* bout = d_in[10];
    const void* c0   = d_in[11];
    const void* h0   = d_in[12];

    char* ws  = (char*)d_ws;
    int* flag = (int*)ws;
    float* out = (float*)d_out;   // OUTPUT IS FP32 (R4/R5 evidence)

    detect_kernel<<<1, 256, 0, stream>>>((const unsigned*)x, flag);

    if (ws_size >= (size_t)FWS_END) {
        float*          c  = (float*)(ws + FWS_C);
        unsigned short* hA = (unsigned short*)(ws + FWS_HA);
        unsigned short* hB = (unsigned short*)(ws + FWS_HB);
        _Float16*       XW = (_Float16*)(ws + FWS_XW);

        init_full_kernel<<<512, 256, 0, stream>>>(c0, h0, flag, c, hA, hB);
        xw_tile_kernel<<<768, 256, 0, stream>>>(x, W, Wi, Wf, Wo, flag, XW);

        for (int t = 0; t < NSTEP; ++t) {
            const unsigned short* hp = (t & 1) ? hB : hA;
            unsigned short*       hn = (t & 1) ? hA : hB;
            step5_kernel<<<G_BLOCKS + 16, 512, 0, stream>>>(
                W, Wi, Wf, Wo, bz, bi, bfg, bo, Wout, bout,
                flag, XW, c, hp, hn, out, t);
        }
        // h(24) lives in hA (t=23 odd wrote hA)
        outproj_final2_kernel<<<32, 512, 0, stream>>>(hA, Wout, bout, flag, out);
    } else {
        _Float16*       c  = (_Float16*)(ws + WS_C);
        unsigned short* hA = (unsigned short*)(ws + WS_HA);
        unsigned short* hB = (unsigned short*)(ws + WS_HB);

        init_kernel<<<512, 256, 0, stream>>>(c0, h0, flag, c, hA, hB);
        for (int t = 0; t < NSTEP; ++t) {
            const unsigned short* hp = (t & 1) ? hB : hA;
            unsigned short*       hn = (t & 1) ? hA : hB;
            gate_cell_kernel<<<256, 256, 0, stream>>>(
                x, W, Wi, Wf, Wo, bz, bi, bfg, bo, flag, c, hp, hn, t);
            outproj_kernel<<<16, 256, 0, stream>>>(hn, Wout, bout, flag, out, t);
        }
    }
}

// Round 16
// 418.544 us; speedup vs baseline: 3.2686x; 1.0061x over previous
//
#include <hip/hip_runtime.h>

#define B_    128
#define NSTEP 24
#define INL   512
#define OUTL  256
#define HL    1024
#define CL    1024
#define IH    (INL + HL)   // 1536
#define G_BLOCKS 256       // gate blocks per step (4 j-cols x 4 gates = 16 rows)

typedef short          s16x8 __attribute__((ext_vector_type(8)));
typedef float          f32x4 __attribute__((ext_vector_type(4)));
typedef unsigned short u16x4 __attribute__((ext_vector_type(4)));
typedef unsigned short u16x8 __attribute__((ext_vector_type(8)));

// ---------- full-path ws layout ----------
// h, c BLOCK-MAJOR: off(b,j) = (j>>2)*512 + b*4 + (j&3)
// XW fp16: ((t*256 + jblk)*128 + b)*16 + jj*4 + g
#define FWS_C   64
#define FWS_HA  (FWS_C + 524288)
#define FWS_HB  (FWS_HA + 262144)
#define FWS_XW  (FWS_HB + 262144)
#define FWS_END (FWS_XW + 25165824)
// ---------- fallback (R5, proven) ----------
#define WS_C  64
#define WS_HA (64 + 262144)
#define WS_HB (64 + 524288)

__device__ __forceinline__ float bits2f(unsigned short u) {
    union { unsigned u; float f; } w; w.u = ((unsigned)u) << 16; return w.f;
}
__device__ __forceinline__ unsigned short f2bf(float f) {
    union { float f; unsigned u; } w; w.f = f;
    unsigned r = (w.u + 0x7fffu + ((w.u >> 16) & 1u)) >> 16;   // RNE
    return (unsigned short)r;
}
__device__ __forceinline__ float sigmoidf_(float v) { return 1.0f / (1.0f + expf(-v)); }
__device__ __forceinline__ float sane(float v, float lim) {   // NaN -> bounded
    return fminf(fmaxf(v, -lim), lim);
}

template<int FP32>
__device__ __forceinline__ s16x8 load8(const void* base, size_t off) {
    if constexpr (FP32) {
        const float* p = (const float*)base + off;
        f32x4 a = *(const f32x4*)p;
        f32x4 b = *(const f32x4*)(p + 4);
        s16x8 r;
        r[0] = (short)f2bf(a[0]); r[1] = (short)f2bf(a[1]);
        r[2] = (short)f2bf(a[2]); r[3] = (short)f2bf(a[3]);
        r[4] = (short)f2bf(b[0]); r[5] = (short)f2bf(b[1]);
        r[6] = (short)f2bf(b[2]); r[7] = (short)f2bf(b[3]);
        return r;
    } else {
        return *(const s16x8*)((const unsigned short*)base + off);
    }
}
template<int FP32>
__device__ __forceinline__ float ld1(const void* base, size_t off) {
    if constexpr (FP32) return ((const float*)base)[off];
    else                return bits2f(((const unsigned short*)base)[off]);
}
template<int FP32>
__device__ __forceinline__ u16x4 ldcvt4(const void* base, size_t off) {
    if constexpr (FP32) {
        f32x4 v = *(const f32x4*)((const float*)base + off);
        u16x4 r;
        r[0] = f2bf(v[0]); r[1] = f2bf(v[1]); r[2] = f2bf(v[2]); r[3] = f2bf(v[3]);
        return r;
    } else {
        return *(const u16x4*)((const unsigned short*)base + off);
    }
}
// A-fragment (8 k-elems) from block-major h; k0 multiple of 8
__device__ __forceinline__ s16x8 ldh8(const unsigned short* __restrict__ h,
                                      int row, int k0) {
    const unsigned short* p = h + (size_t)(k0 >> 2) * 512 + row * 4;
    u16x4 lo = *(const u16x4*)p;
    u16x4 hi = *(const u16x4*)(p + 512);
    s16x8 r;
    r[0] = (short)lo[0]; r[1] = (short)lo[1]; r[2] = (short)lo[2]; r[3] = (short)lo[3];
    r[4] = (short)hi[0]; r[5] = (short)hi[1]; r[6] = (short)hi[2]; r[7] = (short)hi[3];
    return r;
}

// ---------------------------------------------------------------------------
// Dtype detector (verified flag=1/fp32 on this harness in R4).
// ---------------------------------------------------------------------------
__global__ void detect_kernel(const unsigned* __restrict__ xw, int* __restrict__ flag) {
    __shared__ int wild, zero;
    const int tid = threadIdx.x;
    if (tid == 0) { wild = 0; zero = 0; }
    __syncthreads();
    int w = 0, z = 0;
    for (int s = 0; s < 4; ++s) {
        unsigned short lo = (unsigned short)(xw[tid * 4 + s] & 0xffffu);
        float v = bits2f(lo);
        if (v == 0.0f) z++;
        else if (v == v && (fabsf(v) > 1e4f || fabsf(v) < 1e-8f)) w++;
    }
    atomicAdd(&wild, w);
    atomicAdd(&zero, z);
    __syncthreads();
    if (tid == 0) *flag = (wild > 128 || zero > 512) ? 1 : 0;
}

// ===========================================================================
// FULL PATH  (R10 multi-launch structure; persistent variants measured worse
// 3x (R12 1914, R13 971, R14 1368) -> abandoned. R15 = 421 µs baseline.)
// ===========================================================================

// init block-major c/h: linear idx == block-major offset; j = (idx>>9)*4 + (idx&3)
__global__ void init_full_kernel(const void* c0, const void* h0, const int* __restrict__ flag,
                                 float* __restrict__ c,
                                 unsigned short* __restrict__ hA,
                                 unsigned short* __restrict__ hB)
{
    const int f   = *flag;
    const int idx = blockIdx.x * blockDim.x + threadIdx.x;
    if (idx < B_ * CL) {
        const int j = ((idx >> 9) << 2) + (idx & 3);
        c[idx]  = f ? ((const float*)c0)[j] : bits2f(((const unsigned short*)c0)[j]);
        const float hv = f ? ((const float*)h0)[j] : bits2f(((const unsigned short*)h0)[j]);
        const unsigned short hb = f2bf(hv);
        hA[idx] = hb;
        hB[idx] = hb;
    }
}

// ---------------------------------------------------------------------------
// XW tile GEMM — R15 verbatim except occupancy (256,2)->(256,3): all 768
// blocks co-resident (was 1.5 dispatch waves), more latency-hiding. R8's
// occupancy regression was caused by the scattered-store write amplification
// (WRITE 24.6->45 MB); R15's LDS-staged contiguous epilogue removed that
// mechanism (WRITE back to 24.58 MB), so the bump is safe to retest.
// ---------------------------------------------------------------------------
#define XA_PITCH 40
template<int FP32>
__device__ __forceinline__ void xw_tile_body(
    const void* __restrict__ x,
    const void* __restrict__ W,  const void* __restrict__ Wi,
    const void* __restrict__ Wf, const void* __restrict__ Wo,
    _Float16* __restrict__ XW, int t, int j0,
    unsigned short* __restrict__ smem)
{
    unsigned short* Alds = smem;                   // W rows  [128][40]
    unsigned short* Blds = smem + 128 * XA_PITCH;  // x rows  [128][40]

    const int tid  = threadIdx.x;
    const int lane = tid & 63;
    const int wv   = tid >> 6;
    const int c16  = lane & 15;
    const int kg   = lane >> 4;
    const int mq   = wv >> 1, nq = wv & 1;

    int rowc[4], colc[4];
    const void* wbase[4];
    size_t wrow[4];
    #pragma unroll
    for (int p = 0; p < 4; ++p) {
        const int cid = tid + p * 256;
        rowc[p] = cid >> 3;
        colc[p] = (cid & 7) * 4;
        const int g = rowc[p] >> 5;
        wbase[p] = (g == 0) ? W : (g == 1) ? Wi : (g == 2) ? Wf : Wo;
        wrow[p]  = ((size_t)(t * CL + j0 + (rowc[p] & 31))) * IH;
    }

    f32x4 acc[4][4];
    #pragma unroll
    for (int a = 0; a < 4; ++a)
        #pragma unroll
        for (int b = 0; b < 4; ++b) acc[a][b] = (f32x4){0.f, 0.f, 0.f, 0.f};

    u16x4 ra[4], rb[4];
    #pragma unroll
    for (int p = 0; p < 4; ++p) {
        ra[p] = ldcvt4<FP32>(wbase[p], wrow[p] + colc[p]);
        rb[p] = ldcvt4<FP32>(x,  ((size_t)(rowc[p] * NSTEP + t)) * INL + colc[p]);
    }

    for (int s = 0; s < 16; ++s) {
        __syncthreads();
        #pragma unroll
        for (int p = 0; p < 4; ++p) {
            *(u16x4*)(Alds + rowc[p] * XA_PITCH + colc[p]) = ra[p];
            *(u16x4*)(Blds + rowc[p] * XA_PITCH + colc[p]) = rb[p];
        }
        if (s < 15) {
            const int k0 = (s + 1) * 32;
            #pragma unroll
            for (int p = 0; p < 4; ++p) {
                ra[p] = ldcvt4<FP32>(wbase[p], wrow[p] + k0 + colc[p]);
                rb[p] = ldcvt4<FP32>(x,  ((size_t)(rowc[p] * NSTEP + t)) * INL + k0 + colc[p]);
            }
        }
        __syncthreads();
        s16x8 av[4], bv[4];
        #pragma unroll
        for (int mf = 0; mf < 4; ++mf)
            av[mf] = *(const s16x8*)(Alds + (mq * 64 + mf * 16 + c16) * XA_PITCH + kg * 8);
        #pragma unroll
        for (int nf = 0; nf < 4; ++nf)
            bv[nf] = *(const s16x8*)(Blds + (nq * 64 + nf * 16 + c16) * XA_PITCH + kg * 8);
        #pragma unroll
        for (int mf = 0; mf < 4; ++mf)
            #pragma unroll
            for (int nf = 0; nf < 4; ++nf)
                acc[mf][nf] = __builtin_amdgcn_mfma_f32_16x16x32_bf16(av[mf], bv[nf], acc[mf][nf], 0, 0, 0);
    }

    // C-stage via LDS, then contiguous 16B copy-out (R12 epilogue, proven)
    __syncthreads();
    _Float16* lc = (_Float16*)smem;   // [8 jblkL][128 b][4 jj][4 g] = 32 KB
    #pragma unroll
    for (int mf = 0; mf < 4; ++mf)
        #pragma unroll
        for (int nf = 0; nf < 4; ++nf)
            #pragma unroll
            for (int i = 0; i < 4; ++i) {
                const int jr = mq * 64 + mf * 16 + kg * 4 + i;   // 0..127
                const int bc = nq * 64 + nf * 16 + c16;
                const int g  = jr >> 5;
                const int jl = jr & 31;
                lc[(size_t)((jl >> 2) * 128 + bc) * 16 + (jl & 3) * 4 + g] =
                    (_Float16)acc[mf][nf][i];
            }
    __syncthreads();
    _Float16* dst = XW + ((size_t)t * 256 + (j0 >> 2)) * 2048;
    #pragma unroll
    for (int q = 0; q < 8; ++q) {
        const int off = (q * 256 + tid) * 8;
        *(u16x8*)(dst + off) = *(const u16x8*)(lc + off);
    }
}

__global__ __launch_bounds__(256, 3) void xw_tile_kernel(
    const void* x, const void* W, const void* Wi, const void* Wf, const void* Wo,
    const int* __restrict__ flag, _Float16* XW)
{
    __shared__ unsigned short smem[16384];   // 32 KB
    const int blk = blockIdx.x;        // 24*32 = 768
    const int t   = blk >> 5;
    const int j0  = (blk & 31) * 32;
    if (*flag) xw_tile_body<1>(x, W, Wi, Wf, Wo, XW, t, j0, smem);
    else       xw_tile_body<0>(x, W, Wi, Wf, Wo, XW, t, j0, smem);
}

// ---------------------------------------------------------------------------
// step5: grid 272 x 512 thr (R10 verbatim, 13 µs/step proven).
//  blocks 0..255  : gate slice (16 gate-rows = 4 j x 4 gates) + cell update
//  blocks 256..271: outproj(t-1), 16 o-cols each (skip at t=0)
// ---------------------------------------------------------------------------
template<int FP32>
__device__ __forceinline__ void step5_body(
    const void* __restrict__ W,  const void* __restrict__ Wi,
    const void* __restrict__ Wf, const void* __restrict__ Wo,
    const void* __restrict__ bz, const void* __restrict__ bi,
    const void* __restrict__ bfg, const void* __restrict__ bo,
    const void* __restrict__ Wout, const void* __restrict__ bout,
    const _Float16* __restrict__ XW, float* __restrict__ c,
    const unsigned short* __restrict__ hprev,
    unsigned short* __restrict__ hnext,
    float* __restrict__ out, int t)
{
    __shared__ unsigned short smem[16 * 1024];   // 32 KB W tile (XOR-swizzled rows)
    const int blk  = blockIdx.x;
    const int tid  = threadIdx.x;
    const int lane = tid & 63;
    const int wv   = tid >> 6;          // 0..7 -> batch rows [wv*16, wv*16+16)
    const int c16  = lane & 15;
    const int kg   = lane >> 4;
    const bool isOut = (blk >= G_BLOCKS);
    if (isOut && t == 0) return;

    // stage 16 W rows -> LDS bf16, byte ^= (row&7)<<4 swizzle
    {
        const int srow = tid >> 5;            // 0..15
        const int scl  = (tid & 31) * 4;
        const void* wptr;
        size_t woff;
        if (!isOut) {
            const int g = srow >> 2, jj = srow & 3;
            wptr = (g == 0) ? W : (g == 1) ? Wi : (g == 2) ? Wf : Wo;
            woff = ((size_t)(t * CL + blk * 4 + jj)) * IH + INL;
        } else {
            wptr = Wout;
            woff = ((size_t)((t - 1) * OUTL + (blk - G_BLOCKS) * 16 + srow)) * HL;
        }
        const unsigned swz = (unsigned)((srow & 7) << 4);
        #pragma unroll
        for (int i = 0; i < 8; ++i) {
            const int col = scl + i * 128;
            u16x4 v = ldcvt4<FP32>(wptr, woff + col);
            *(u16x4*)((char*)smem + srow * 2048 + (((unsigned)(col * 2)) ^ swz)) = v;
        }
    }
    __syncthreads();

    // MFMA: wave wv = 16 batch rows x block's 16 cols, K = 1024
    const int row = wv * 16 + c16;
    const char* brow = (const char*)smem + c16 * 2048;
    const unsigned cswz = (unsigned)((c16 & 7) << 4);
    f32x4 acc = {0.f, 0.f, 0.f, 0.f};
    #pragma unroll 8
    for (int kb = 0; kb < HL; kb += 32) {
        s16x8 av = ldh8(hprev, row, kb + kg * 8);
        s16x8 bv = *(const s16x8*)(brow + (((unsigned)((kb + kg * 8) * 2)) ^ cswz));
        acc = __builtin_amdgcn_mfma_f32_16x16x32_bf16(av, bv, acc, 0, 0, 0);
    }

    if (isOut) {
        // C/D: row(batch) = wv*16 + kg*4 + i, col = c16
        const int o = (blk - G_BLOCKS) * 16 + c16;
        const float bb = ld1<FP32>(bout, (size_t)(t - 1) * OUTL + o);
        #pragma unroll
        for (int i = 0; i < 4; ++i) {
            const int b = wv * 16 + kg * 4 + i;
            out[(size_t)b * (NSTEP * OUTL) + (size_t)(t - 1) * OUTL + o] =
                sigmoidf_(sane(acc[i] + bb, 30.f));
        }
        return;
    }

    // gate: redistribute logits via LDS (aliases W tile), cell update
    __syncthreads();
    float* lsm = (float*)smem;          // [16 cols][130 rows]
    #pragma unroll
    for (int i = 0; i < 4; ++i)
        lsm[c16 * 130 + wv * 16 + kg * 4 + i] = acc[i];
    __syncthreads();

    // cell update: tid = b*4 + jq -> writes h/c at blk*512 + tid (coalesced)
    const int b  = tid >> 2;
    const int jq = tid & 3;
    const int jg = blk * 4 + jq;
    u16x4 xv = *(const u16x4*)((const unsigned short*)XW +
                               (((size_t)t * 256 + blk) * B_ + b) * 16 + jq * 4);
    union { unsigned short u; _Float16 h; } cv0, cv1, cv2, cv3;
    cv0.u = xv[0]; cv1.u = xv[1]; cv2.u = xv[2]; cv3.u = xv[3];
    const float l0 = lsm[(0 * 4 + jq) * 130 + b] + (float)cv0.h
                   + ld1<FP32>(bz,  (size_t)t * CL + jg);
    const float l1 = lsm[(1 * 4 + jq) * 130 + b] + (float)cv1.h
                   + ld1<FP32>(bi,  (size_t)t * CL + jg);
    const float l2 = lsm[(2 * 4 + jq) * 130 + b] + (float)cv2.h
                   + ld1<FP32>(bfg, (size_t)t * CL + jg);
    const float l3 = lsm[(3 * 4 + jq) * 130 + b] + (float)cv3.h
                   + ld1<FP32>(bo,  (size_t)t * CL + jg);
    const float z  = tanhf(sane(l0, 30.f));
    const float zi = sigmoidf_(sane(l1, 30.f));
    const float zf = sigmoidf_(sane(l2, 30.f));
    const float zo = sigmoidf_(sane(l3, 30.f));
    const size_t soff = (size_t)blk * 512 + tid;
    const float cold = c[soff];
    const float cn   = sane(zf * cold + zi * z, 50.f);
    c[soff] = cn;
    hnext[soff] = f2bf(zo * tanhf(cn));
}

__global__ __launch_bounds__(512, 4) void step5_kernel(
    const void* W, const void* Wi, const void* Wf, const void* Wo,
    const void* bz, const void* bi, const void* bfg, const void* bo,
    const void* Wout, const void* bout,
    const int* __restrict__ flag, const _Float16* XW, float* c,
    const unsigned short* hprev, unsigned short* hnext, float* out, int t)
{
    if (*flag) step5_body<1>(W, Wi, Wf, Wo, bz, bi, bfg, bo, Wout, bout, XW, c, hprev, hnext, out, t);
    else       step5_body<0>(W, Wi, Wf, Wo, bz, bi, bfg, bo, Wout, bout, XW, c, hprev, hnext, out, t);
}

// ---------------------------------------------------------------------------
// Outproj quarter-tile (R10 verbatim; block-major h A-loads).
// ---------------------------------------------------------------------------
template<int FP32>
__device__ __forceinline__ void outproj_part(
    const unsigned short* __restrict__ h, const void* __restrict__ Wout,
    const void* __restrict__ bout, float* __restrict__ out, int tp, int og,
    int tid, float* __restrict__ red)
{
    const int lane = tid & 63;
    const int wv   = tid >> 6;          // 0..3
    const int c16  = lane & 15;
    const int kg   = lane >> 4;
    const int mf   = wv & 1;
    const int kh   = wv >> 1;

    const int o0   = (og & 15) * 16;
    const int mgrp = og >> 4;
    const int o    = o0 + c16;

    const size_t woff = ((size_t)tp * OUTL + o) * HL + kh * 512 + kg * 8;
    const int row = mgrp * 32 + mf * 16 + c16;

    f32x4 acc = {0.f, 0.f, 0.f, 0.f};
    #pragma unroll 8
    for (int kb = 0; kb < 512; kb += 32) {
        s16x8 av = ldh8(h, row, kh * 512 + kb + kg * 8);
        s16x8 bv = load8<FP32>(Wout, woff + kb);
        acc = __builtin_amdgcn_mfma_f32_16x16x32_bf16(av, bv, acc, 0, 0, 0);
    }
    #pragma unroll
    for (int i = 0; i < 4; ++i)
        red[((kh * 2 + mf) * 16 + c16) * 16 + kg * 4 + i] = acc[i];
    __syncthreads();

    const float bb = ld1<FP32>(bout, (size_t)tp * OUTL + o0 + (tid & 15));
    #pragma unroll
    for (int p = 0; p < 2; ++p) {
        const int idx = tid + p * 256;
        const int cc  = idx & 15;
        const int r   = idx >> 4;
        const int mff = r >> 4, rm = r & 15;
        const float lgv = red[(mff * 16 + cc) * 16 + rm]
                        + red[((2 + mff) * 16 + cc) * 16 + rm] + bb;
        out[(size_t)(mgrp * 32 + r) * (NSTEP * OUTL) + (size_t)tp * OUTL + o0 + cc] =
            sigmoidf_(sane(lgv, 30.f));
    }
}

__global__ __launch_bounds__(512, 4) void outproj_final2_kernel(
    const unsigned short* h, const void* Wout, const void* bout,
    const int* __restrict__ flag, float* out)
{
    __shared__ float red[2048];
    const int tid  = threadIdx.x;
    const int half = tid >> 8;
    const int og   = blockIdx.x * 2 + half;
    if (*flag) outproj_part<1>(h, Wout, bout, out, NSTEP - 1, og, tid & 255, red + half * 1024);
    else       outproj_part<0>(h, Wout, bout, out, NSTEP - 1, og, tid & 255, red + half * 1024);
}

// ===========================================================================
// FALLBACK PATH (R5 verbatim, proven)
// ===========================================================================
template<int FP32>
__device__ __forceinline__ void gate_body(
    const void* __restrict__ x,
    const void* __restrict__ W,  const void* __restrict__ Wi,
    const void* __restrict__ Wf, const void* __restrict__ Wo,
    const void* __restrict__ bz, const void* __restrict__ bi,
    const void* __restrict__ bfg, const void* __restrict__ bo,
    _Float16* __restrict__ c,
    const unsigned short* __restrict__ hprev,
    unsigned short* __restrict__ hnext, int t)
{
    const int tid  = threadIdx.x;
    const int lane = tid & 63;
    const int wv   = tid >> 6;
    const int j0   = blockIdx.x * 4;
    const int c16  = lane & 15;
    const int g    = c16 >> 2;
    const int jj   = c16 & 3;
    const int kg   = lane >> 4;

    const void* Wg = (g == 0) ? W : (g == 1) ? Wi : (g == 2) ? Wf : Wo;
    const size_t woff = ((size_t)t * CL + (j0 + jj)) * IH + kg * 8;
    const int row0 = wv * 32 + c16;
    const int row1 = row0 + 16;

    f32x4 acc0 = {0.f, 0.f, 0.f, 0.f};
    f32x4 acc1 = {0.f, 0.f, 0.f, 0.f};
    {
        const size_t a0 = ((size_t)row0 * NSTEP + t) * INL + kg * 8;
        const size_t a1 = ((size_t)row1 * NSTEP + t) * INL + kg * 8;
        #pragma unroll 4
        for (int kb = 0; kb < INL; kb += 32) {
            s16x8 av0 = load8<FP32>(x, a0 + kb);
            s16x8 av1 = load8<FP32>(x, a1 + kb);
            s16x8 bv  = load8<FP32>(Wg, woff + kb);
            acc0 = __builtin_amdgcn_mfma_f32_16x16x32_bf16(av0, bv, acc0, 0, 0, 0);
            acc1 = __builtin_amdgcn_mfma_f32_16x16x32_bf16(av1, bv, acc1, 0, 0, 0);
        }
    }
    {
        const unsigned short* a0 = hprev + (size_t)row0 * HL + kg * 8;
        const unsigned short* a1 = hprev + (size_t)row1 * HL + kg * 8;
        const size_t w2 = woff + INL;
        #pragma unroll 4
        for (int kb = 0; kb < HL; kb += 32) {
            s16x8 av0 = *(const s16x8*)(a0 + kb);
            s16x8 av1 = *(const s16x8*)(a1 + kb);
            s16x8 bv  = load8<FP32>(Wg, w2 + kb);
            acc0 = __builtin_amdgcn_mfma_f32_16x16x32_bf16(av0, bv, acc0, 0, 0, 0);
            acc1 = __builtin_amdgcn_mfma_f32_16x16x32_bf16(av1, bv, acc1, 0, 0, 0);
        }
    }
    __shared__ float lg[4][4][B_];
    #pragma unroll
    for (int i = 0; i < 4; ++i) {
        lg[g][jj][wv * 32 + kg * 4 + i]      = acc0[i];
        lg[g][jj][wv * 32 + 16 + kg * 4 + i] = acc1[i];
    }
    __syncthreads();
    #pragma unroll
    for (int p = 0; p < 2; ++p) {
        const int idx = tid + p * 256;
        const int b   = idx & 127;
        const int jl  = idx >> 7;
        const int jg  = j0 + jl;
        const float z  = tanhf   (sane(lg[0][jl][b] + ld1<FP32>(bz,  t * CL + jg), 30.f));
        const float zi = sigmoidf_(sane(lg[1][jl][b] + ld1<FP32>(bi,  t * CL + jg), 30.f));
        const float zf = sigmoidf_(sane(lg[2][jl][b] + ld1<FP32>(bfg, t * CL + jg), 30.f));
        const float zo = sigmoidf_(sane(lg[3][jl][b] + ld1<FP32>(bo,  t * CL + jg), 30.f));
        const float cold = (float)c[(size_t)b * CL + jg];
        const float cn   = sane(zf * cold + zi * z, 50.f);
        c[(size_t)b * CL + jg] = (_Float16)cn;
        hnext[(size_t)b * HL + jg] = f2bf(zo * tanhf(cn));
    }
}

__global__ __launch_bounds__(256, 1) void gate_cell_kernel(
    const void* x, const void* W, const void* Wi, const void* Wf, const void* Wo,
    const void* bz, const void* bi, const void* bfg, const void* bo,
    const int* __restrict__ flag, _Float16* c,
    const unsigned short* hprev, unsigned short* hnext, int t)
{
    if (*flag) gate_body<1>(x, W, Wi, Wf, Wo, bz, bi, bfg, bo, c, hprev, hnext, t);
    else       gate_body<0>(x, W, Wi, Wf, Wo, bz, bi, bfg, bo, c, hprev, hnext, t);
}

template<int FP32>
__device__ __forceinline__ void outproj_body(
    const unsigned short* __restrict__ h, const void* __restrict__ Wout,
    const void* __restrict__ bout, float* __restrict__ out, int t)
{
    const int tid  = threadIdx.x;
    const int lane = tid & 63;
    const int wv   = tid >> 6;
    const int o    = blockIdx.x * 16 + (lane & 15);
    const int kg   = lane >> 4;
    const size_t woff = ((size_t)t * OUTL + o) * HL + kg * 8;
    const int row0 = wv * 32 + (lane & 15);
    const int row1 = row0 + 16;
    const unsigned short* a0 = h + (size_t)row0 * HL + kg * 8;
    const unsigned short* a1 = h + (size_t)row1 * HL + kg * 8;

    f32x4 acc0 = {0.f, 0.f, 0.f, 0.f};
    f32x4 acc1 = {0.f, 0.f, 0.f, 0.f};
    #pragma unroll 4
    for (int kb = 0; kb < HL; kb += 32) {
        s16x8 av0 = *(const s16x8*)(a0 + kb);
        s16x8 av1 = *(const s16x8*)(a1 + kb);
        s16x8 bv  = load8<FP32>(Wout, woff + kb);
        acc0 = __builtin_amdgcn_mfma_f32_16x16x32_bf16(av0, bv, acc0, 0, 0, 0);
        acc1 = __builtin_amdgcn_mfma_f32_16x16x32_bf16(av1, bv, acc1, 0, 0, 0);
    }
    const float bb = ld1<FP32>(bout, (size_t)t * OUTL + o);
    #pragma unroll
    for (int i = 0; i < 4; ++i) {
        const int r0 = wv * 32 + kg * 4 + i;
        out[(size_t)r0 * (NSTEP * OUTL) + (size_t)t * OUTL + o] =
            sigmoidf_(sane(acc0[i] + bb, 30.f));
        out[(size_t)(r0 + 16) * (NSTEP * OUTL) + (size_t)t * OUTL + o] =
            sigmoidf_(sane(acc1[i] + bb, 30.f));
    }
}

__global__ __launch_bounds__(256, 1) void outproj_kernel(
    const unsigned short* h, const void* Wout, const void* bout,
    const int* __restrict__ flag, float* out, int t)
{
    if (*flag) outproj_body<1>(h, Wout, bout, out, t);
    else       outproj_body<0>(h, Wout, bout, out, t);
}

__global__ void init_kernel(const void* c0, const void* h0, const int* __restrict__ flag,
                            _Float16* __restrict__ c,
                            unsigned short* __restrict__ hA,
                            unsigned short* __restrict__ hB)
{
    const int f   = *flag;
    const int idx = blockIdx.x * blockDim.x + threadIdx.x;
    if (idx < B_ * CL) {
        const int j = idx & (CL - 1);
        const float cv = f ? ((const float*)c0)[j] : bits2f(((const unsigned short*)c0)[j]);
        const float hv = f ? ((const float*)h0)[j] : bits2f(((const unsigned short*)h0)[j]);
        c[idx]  = (_Float16)cv;
        const unsigned short hb = f2bf(hv);
        hA[idx] = hb;
        hB[idx] = hb;
    }
}

// ===========================================================================
extern "C" void kernel_launch(void* const* d_in, const int* in_sizes, int n_in,
                              void* d_out, int out_size, void* d_ws, size_t ws_size,
                              hipStream_t stream)
{
    const void* x    = d_in[0];
    const void* W    = d_in[1];
    const void* Wi   = d_in[2];
    const void* Wf   = d_in[3];
    const void* Wo   = d_in[4];
    const void* Wout = d_in[5];
    const void* bz   = d_in[6];
    const void* bi   = d_in[7];
    const void* bfg  = d_in[8];
    const void* bo   = d_in[9];
    const void* bout = d_in[10];
    const void* c0   = d_in[11];
    const void* h0   = d_in[12];

    char* ws  = (char*)d_ws;
    int* flag = (int*)ws;
    float* out = (float*)d_out;   // OUTPUT IS FP32 (R4/R5 evidence)

    detect_kernel<<<1, 256, 0, stream>>>((const unsigned*)x, flag);

    if (ws_size >= (size_t)FWS_END) {
        float*          c  = (float*)(ws + FWS_C);
        unsigned short* hA = (unsigned short*)(ws + FWS_HA);
        unsigned short* hB = (unsigned short*)(ws + FWS_HB);
        _Float16*       XW = (_Float16*)(ws + FWS_XW);

        init_full_kernel<<<512, 256, 0, stream>>>(c0, h0, flag, c, hA, hB);
        xw_tile_kernel<<<768, 256, 0, stream>>>(x, W, Wi, Wf, Wo, flag, XW);

        for (int t = 0; t < NSTEP; ++t) {
            const unsigned short* hp = (t & 1) ? hB : hA;
            unsigned short*       hn = (t & 1) ? hA : hB;
            step5_kernel<<<G_BLOCKS + 16, 512, 0, stream>>>(
                W, Wi, Wf, Wo, bz, bi, bfg, bo, Wout, bout,
                flag, XW, c, hp, hn, out, t);
        }
        // h(24) lives in hA (t=23 odd wrote hA)
        outproj_final2_kernel<<<32, 512, 0, stream>>>(hA, Wout, bout, flag, out);
    } else {
        _Float16*       c  = (_Float16*)(ws + WS_C);
        unsigned short* hA = (unsigned short*)(ws + WS_HA);
        unsigned short* hB = (unsigned short*)(ws + WS_HB);

        init_kernel<<<512, 256, 0, stream>>>(c0, h0, flag, c, hA, hB);
        for (int t = 0; t < NSTEP; ++t) {
            const unsigned short* hp = (t & 1) ? hB : hA;
            unsigned short*       hn = (t & 1) ? hA : hB;
            gate_cell_kernel<<<256, 256, 0, stream>>>(
                x, W, Wi, Wf, Wo, bz, bi, bfg, bo, flag, c, hp, hn, t);
            outproj_kernel<<<16, 256, 0, stream>>>(hn, Wout, bout, flag, out, t);
        }
    }
}